// Round 2
// baseline (410.439 us; speedup 1.0000x reference)
//
#include <hip/hip_runtime.h>
#include <cstdint>

typedef unsigned long long u64;
typedef unsigned int u32;

#define NB 4096
#define NW 64            // 64-bit words per mask row
#define MM 20
#define HH 16
#define GRID_BLOCKS 256
#define COND_THRES 0.2f
#define IOU_THRES 0.3f
#define PI_F  3.14159265358979323846f
#define PI4_F 0.78539816339744830962f

// ---- workspace layout (bytes) ----
#define WS_KEPT    0                           // u64[64] kept bitmask
#define WS_CNT     1024                        // u32 grid-barrier counter
#define WS_MASK    32768                       // u64[NB*NW] = 2 MiB
#define WS_BOX9S   (WS_MASK + NB*NW*8)         // float[NB*9]
#define WS_BEVS    (WS_BOX9S + NB*9*4)         // float4[NB]
#define WS_SCORES  (WS_BEVS + NB*16)           // float[NB]
#define WS_LABELS  (WS_SCORES + NB*4)          // int[NB]
#define WS_NBRW    (WS_LABELS + NB*4)          // u64[NB]
#define WS_PART    (WS_NBRW + NB*8)            // u32[NB*16] rank partials

__device__ __forceinline__ u64 sort_key(float s, int i) {
  u32 sb = (s > COND_THRES) ? __float_as_uint(s) : 0u;
  return ((u64)(sb ^ 0xFFFFFFFFu) << 12) | (u64)i;
}

// Grid-wide barrier: monotonic counter, device-scope atomics.
// Safe because the whole grid is guaranteed co-resident (256 blocks x 16 waves
// at <=128 VGPR, ~27KB LDS -> >=1 block/CU on 256 CUs).
// __threadfence() on gfx95x emits the agent-scope L2 writeback/invalidate
// required for cross-XCD visibility (G16).
__device__ __forceinline__ void grid_sync(u32* cnt, u32 target) {
  __syncthreads();
  if (threadIdx.x == 0) {
    __threadfence();                    // release: flush this XCD's dirty L2
    atomicAdd(cnt, 1u);
    while (atomicAdd(cnt, 0u) < target) __builtin_amdgcn_s_sleep(2);
  }
  __syncthreads();
  __threadfence();                      // acquire: invalidate stale lines
}

#define POOL_BYTES 25600   // max(S1 2KB, S3 20KB, S5 16*1600B)

__global__ void __launch_bounds__(1024) k_mega(
    const float* __restrict__ boxes9, const float* __restrict__ scores,
    const int* __restrict__ labels,
    const float* __restrict__ w1, const float* __restrict__ b1,
    const float* __restrict__ w2, const float* __restrict__ b2,
    const float* __restrict__ w3, const float* __restrict__ b3,
    float* __restrict__ out,
    u64* __restrict__ mask, float* __restrict__ box9s, float4* __restrict__ bevs,
    float* __restrict__ scoress, int* __restrict__ labelss,
    u64* __restrict__ nbrw, u32* __restrict__ partial,
    u64* __restrict__ keptOut, u32* __restrict__ barCnt) {
  #pragma clang fp contract(off)
  __shared__ __align__(16) char pool[POOL_BYTES];
  __shared__ u64 nms_decided[64], nms_kept[64];
  __shared__ int nms_wavePending[16];
  __shared__ int nms_any;
  const int tid = threadIdx.x;
  const int bid = blockIdx.x;

  // ================= S1: counting-rank partials + nbrw zero =================
  {
    u64* kj = (u64*)pool;                       // 2 KB
    int bj = bid & 15, bi = bid >> 4;
    if (tid < 256) kj[tid] = sort_key(scores[bj * 256 + tid], bj * 256 + tid);
    __syncthreads();
    if (tid < 256) {
      int i = bi * 256 + tid;
      if (bj == 0) nbrw[i] = 0;
      u64 ki = sort_key(scores[i], i);
      int c = 0;
      #pragma unroll 16
      for (int t2 = 0; t2 < 256; ++t2) c += (kj[t2] < ki) ? 1 : 0;  // LDS broadcast
      partial[i * 16 + bj] = (u32)c;
    }
  }
  grid_sync(barCnt, 1 * GRID_BLOCKS);

  // ================= S2: rank sum + scatter (blocks 0..3) =================
  if (bid < 4) {
    int i = bid * 1024 + tid;
    const uint4* p4 = (const uint4*)(partial + i * 16);
    uint4 a0 = p4[0], a1 = p4[1], a2 = p4[2], a3 = p4[3];
    int r = (int)(a0.x + a0.y + a0.z + a0.w + a1.x + a1.y + a1.z + a1.w +
                  a2.x + a2.y + a2.z + a2.w + a3.x + a3.y + a3.z + a3.w);
    float b[9];
    #pragma unroll
    for (int f = 0; f < 9; ++f) b[f] = boxes9[i * 9 + f];
    #pragma unroll
    for (int f = 0; f < 9; ++f) box9s[r * 9 + f] = b[f];
    float ang = b[6] - floorf(b[6] / PI_F + 0.5f) * PI_F;
    bool sw = fabsf(ang) >= PI4_F;
    float dx = sw ? b[4] : b[3];
    float dy = sw ? b[3] : b[4];
    bevs[r] = make_float4(b[0] - dx * 0.5f, b[1] - dy * 0.5f,
                          b[0] + dx * 0.5f, b[1] + dy * 0.5f);
    scoress[r] = scores[i];
    labelss[r] = labels[i];
  }
  grid_sync(barCnt, 2 * GRID_BLOCKS);

  // ================= S3: pairwise over-matrix, 1 tile per wave =================
  {
    int waveId = tid >> 6;
    int lane = tid & 63;
    float4* bjW = ((float4*)pool) + waveId * 64;          // 16 KB
    int* ljW = ((int*)(pool + 16384)) + waveId * 64;      // 4 KB
    int wave = (bid << 4) | waveId;                       // tile id in [0,4096)
    int it = wave >> 6, jt = wave & 63;
    int i = (it << 6) | lane;
    int j = (jt << 6) | lane;
    float4 a = bevs[i];
    int la = labelss[i];
    float area_a = (a.z - a.x) * (a.w - a.y);
    bjW[lane] = bevs[j];
    ljW[lane] = labelss[j];
    u64 vj = __ballot(scoress[j] > COND_THRES);   // valid mask of this j-tile
    __syncthreads();
    u64 w = 0;
    #pragma unroll 8
    for (int kk = 0; kk < 64; ++kk) {
      float4 bb = bjW[kk];
      float xmin = fmaxf(a.x, bb.x), ymin = fmaxf(a.y, bb.y);
      float xmax = fminf(a.z, bb.z), ymax = fminf(a.w, bb.w);
      float inter = fmaxf(xmax - xmin, 0.0f) * fmaxf(ymax - ymin, 0.0f);
      float area_b = (bb.z - bb.x) * (bb.w - bb.y);
      float iou = inter / fmaxf(area_a + area_b - inter, 1e-6f);
      if ((iou > IOU_THRES) && (la == ljW[kk])) w |= (1ull << kk);
    }
    mask[(u64)i * NW + jt] = w;
    if (jt <= it) {
      u64 below = (jt < it) ? ~0ull : ((1ull << lane) - 1ull);
      if (w & vj & below) atomicOr(&nbrw[i], 1ull << jt);
    }
  }
  grid_sync(barCnt, 3 * GRID_BLOCKS);

  // ================= S4: greedy NMS fixpoint (block 0 only) =================
  if (bid == 0) {
    int lane = tid & 63;
    int waveId = tid >> 6;
    u64 dcache[4], kcache[4];
    #pragma unroll
    for (int s = 0; s < 4; ++s) {
      int i = tid + (s << 10);
      bool v = scoress[i] > COND_THRES;
      u64 vw = __ballot(v);
      dcache[s] = ~vw;
      kcache[s] = 0;
      if (lane == 0) {
        int wi = waveId + (s << 4);
        nms_decided[wi] = ~vw;
        nms_kept[wi] = 0;
      }
    }
    // register cache: up to 2 masked neighbor words per owned box
    u64 cw0[4], cw1[4];
    u32 meta[4];   // [5:0] idx0, [11:6] idx1, [13:12] n(min 2), [14] overflow
    #pragma unroll
    for (int s = 0; s < 4; ++s) {
      int i = tid + (s << 10);
      int wi = i >> 6;
      u64 bit = 1ull << (i & 63);
      u64 t = nbrw[i];
      int n = 0; u32 ovf = 0;
      u64 c0 = 0, c1 = 0; u32 i0 = 0, i1 = 0;
      while (t) {
        int w = __builtin_ctzll(t);
        t &= t - 1;
        u64 below = (w < wi) ? ~0ull : (bit - 1ull);
        u64 m = mask[(u64)i * NW + w] & below;
        if (n == 0)      { c0 = m; i0 = (u32)w; }
        else if (n == 1) { c1 = m; i1 = (u32)w; }
        else ovf = 1;
        ++n;
      }
      cw0[s] = c0; cw1[s] = c1;
      meta[s] = i0 | (i1 << 6) | ((u32)(n > 2 ? 2 : n) << 12) | (ovf << 14);
    }
    __syncthreads();
    while (true) {
      bool pend = false;
      #pragma unroll
      for (int s = 0; s < 4; ++s) {
        bool mine_und = !((dcache[s] >> lane) & 1ull);
        bool dec = false, keepme = false;
        if (mine_und) {
          bool hasU = false, hasK = false;
          u32 mt = meta[s];
          if (!(mt & (1u << 14))) {
            int n = (mt >> 12) & 3;
            if (n >= 1) {
              int w = mt & 63;
              u64 dw = nms_decided[w], kw = nms_kept[w];
              hasU = (cw0[s] & ~dw) != 0ull;
              hasK = (cw0[s] & kw) != 0ull;
            }
            if (n >= 2) {
              int w = (mt >> 6) & 63;
              u64 dw = nms_decided[w], kw = nms_kept[w];
              hasU = hasU || ((cw1[s] & ~dw) != 0ull);
              hasK = hasK || ((cw1[s] & kw) != 0ull);
            }
          } else {
            int i = tid + (s << 10);
            int wi = i >> 6;
            u64 bit = 1ull << (i & 63);
            u64 t = nbrw[i];
            while (t) {
              int w = __builtin_ctzll(t);
              t &= t - 1;
              u64 below = (w < wi) ? ~0ull : (bit - 1ull);
              u64 m = mask[(u64)i * NW + w] & below;
              hasU = hasU || ((m & ~nms_decided[w]) != 0ull);
              hasK = hasK || ((m & nms_kept[w]) != 0ull);
            }
          }
          dec = !hasU;
          keepme = !hasK;
        }
        u64 b_nd = __ballot(dec);
        u64 b_nk = __ballot(dec && keepme);
        dcache[s] |= b_nd;
        kcache[s] |= b_nk;
        pend |= (mine_und && !dec);
      }
      u64 pw = __ballot(pend);
      if (lane == 0) nms_wavePending[waveId] = (pw != 0ull) ? 1 : 0;
      __syncthreads();
      if (lane == 0) {
        #pragma unroll
        for (int s = 0; s < 4; ++s) {
          int wi = waveId + (s << 4);
          nms_decided[wi] = dcache[s];
          nms_kept[wi] = kcache[s];
        }
      }
      if (tid == 0) {
        int any = 0;
        #pragma unroll
        for (int w = 0; w < 16; ++w) any |= nms_wavePending[w];
        nms_any = any;
      }
      __syncthreads();
      if (!nms_any) break;
    }
    if (tid < 64) keptOut[tid] = nms_kept[tid];
  }
  grid_sync(barCnt, 4 * GRID_BLOCKS);

  // ================= S5: per-box merge + outputs, 1 box per wave =================
  {
    if (tid < 64) nms_kept[tid] = keptOut[tid];   // K cache (all blocks)
    __syncthreads();                              // B0
    int waveId = tid >> 6;
    int lane = tid & 63;
    int i = (bid << 4) | waveId;                  // sorted box id
    char* ws5 = pool + waveId * 1600;             // per-wave scratch (disjoint)
    float (*ob)[7]  = (float(*)[7])(ws5);         // 560 B
    float (*h1)[HH] = (float(*)[HH])(ws5 + 560);  // 448 B
    float (*h2)[HH] = (float(*)[HH])(ws5 + 1008); // 448 B
    float* res      = (float*)(ws5 + 1456);       // 28 B
    int* candList   = (int*)(ws5 + 1484);         // 80 B
    bool active = (nms_kept[i >> 6] >> (i & 63)) & 1ull;
    u64 wq = 0;
    int cnt = 0;
    if (active) {
      u64 w = mask[(u64)i * NW + lane];
      int hiw = i >> 6;
      u64 below = (1ull << (i & 63)) - 1ull;
      while (w) {
        int b = __builtin_ctzll(w);
        w &= w - 1;
        int j = (lane << 6) | b;
        if (scoress[j] > COND_THRES) {
          // claimed := exists kept k < i with over(k, j)
          const u64* rowj = mask + (u64)j * NW;
          u64 found = rowj[hiw] & nms_kept[hiw] & below;
          for (int ww = 0; ww < hiw; ++ww) found |= rowj[ww] & nms_kept[ww];
          if (!found) { wq |= (1ull << b); cnt++; }
        }
      }
    }
    int incl = cnt;
    #pragma unroll
    for (int off = 1; off < 64; off <<= 1) {
      int v = __shfl_up(incl, off);
      if (lane >= off) incl += v;
    }
    int excl = incl - cnt;
    int count = __shfl(incl, 63);
    bool merged = active && (count > 1);
    if (merged && wq) {
      int pos = excl;
      u64 ww = wq;
      while (ww && pos < MM) {
        int b = __builtin_ctzll(ww);
        ww &= ww - 1;
        candList[pos++] = (lane << 6) | b;
      }
    }
    __syncthreads();                              // B1
    int nc = count < MM ? count : MM;
    if (merged && lane < MM) {
      if (lane < nc) {
        int j = candList[lane];
        #pragma unroll
        for (int f = 0; f < 7; ++f) ob[lane][f] = box9s[j * 9 + f];
      } else {
        #pragma unroll
        for (int f = 0; f < 7; ++f) ob[lane][f] = 0.0f;
      }
    }
    __syncthreads();                              // B2
    if (merged) {
      for (int o = lane; o < 7 * HH; o += 64) {
        int f = o >> 4, hh = o & 15;
        float acc = b1[hh];
        #pragma unroll
        for (int m = 0; m < MM; ++m) acc += ob[m][f] * w1[m * HH + hh];
        h1[f][hh] = fmaxf(acc, 0.0f);
      }
    }
    __syncthreads();                              // B3
    if (merged) {
      for (int o = lane; o < 7 * HH; o += 64) {
        int f = o >> 4, oo = o & 15;
        float acc = b2[oo];
        #pragma unroll
        for (int k = 0; k < HH; ++k) acc += h1[f][k] * w2[k * HH + oo];
        h2[f][oo] = fmaxf(acc, 0.0f);
      }
    }
    __syncthreads();                              // B4
    if (merged && lane < 7) {
      float acc = b3[0];
      #pragma unroll
      for (int k = 0; k < HH; ++k) acc += h2[lane][k] * w3[k];
      if (lane >= 3 && lane < 6) acc = fmaxf(acc, 1e-5f);
      res[lane] = acc;
    }
    __syncthreads();                              // B5
    if (lane < 9) {
      float v = box9s[i * 9 + lane];
      if (merged && lane < 7) v = res[lane];
      out[i * 9 + lane] = v;
    }
    if (lane == 0) {
      out[NB * 9 + i]          = scoress[i];
      out[NB * 9 + NB + i]     = (float)labelss[i];
      out[NB * 9 + 2 * NB + i] = active ? 1.0f : 0.0f;
    }
  }
}

extern "C" void kernel_launch(void* const* d_in, const int* in_sizes, int n_in,
                              void* d_out, int out_size, void* d_ws, size_t ws_size,
                              hipStream_t stream) {
  const float* boxes9 = (const float*)d_in[0];
  const float* scores = (const float*)d_in[1];
  const int*   labels = (const int*)d_in[2];
  const float* w1 = (const float*)d_in[3];
  const float* b1 = (const float*)d_in[4];
  const float* w2 = (const float*)d_in[5];
  const float* b2 = (const float*)d_in[6];
  const float* w3 = (const float*)d_in[7];
  const float* b3 = (const float*)d_in[8];
  char* ws = (char*)d_ws;
  u64*    kept    = (u64*)(ws + WS_KEPT);
  u64*    mask    = (u64*)(ws + WS_MASK);
  float*  box9s   = (float*)(ws + WS_BOX9S);
  float4* bevs    = (float4*)(ws + WS_BEVS);
  float*  scoress = (float*)(ws + WS_SCORES);
  int*    labelss = (int*)(ws + WS_LABELS);
  u64*    nbrw    = (u64*)(ws + WS_NBRW);
  u32*    part    = (u32*)(ws + WS_PART);
  u32*    barCnt  = (u32*)(ws + WS_CNT);
  float*  out     = (float*)d_out;

  hipMemsetAsync(barCnt, 0, sizeof(u32), stream);
  hipLaunchKernelGGL(k_mega, dim3(GRID_BLOCKS), dim3(1024), 0, stream,
                     boxes9, scores, labels, w1, b1, w2, b2, w3, b3, out,
                     mask, box9s, bevs, scoress, labelss, nbrw, part, kept, barCnt);
}

// Round 3
// 125.813 us; speedup vs baseline: 3.2623x; 3.2623x over previous
//
#include <hip/hip_runtime.h>
#include <cstdint>

typedef unsigned long long u64;
typedef unsigned int u32;

#define NB 4096
#define NW 64            // 64-bit words per mask row
#define MM 20
#define HH 16
#define COND_THRES 0.2f
#define IOU_THRES 0.3f
#define PI_F  3.14159265358979323846f
#define PI4_F 0.78539816339744830962f

// ---- workspace layout (bytes) ----
#define WS_KEPT    0                           // u64[64] kept bitmask
#define WS_FLAG    1024                        // u32 producer->consumer flag
#define WS_MASK    32768                       // u64[NB*NW] = 2 MiB
#define WS_BOX9S   (WS_MASK + NB*NW*8)         // float[NB*9]
#define WS_BEVS    (WS_BOX9S + NB*9*4)         // float4[NB]
#define WS_SCORES  (WS_BEVS + NB*16)           // float[NB]
#define WS_LABELS  (WS_SCORES + NB*4)          // int[NB]
#define WS_NBRW    (WS_LABELS + NB*4)          // u64[NB]

__device__ __forceinline__ u64 sort_key(float s, int i) {
  u32 sb = (s > COND_THRES) ? __float_as_uint(s) : 0u;
  return ((u64)(sb ^ 0xFFFFFFFFu) << 12) | (u64)i;
}

// ---------- K1: full counting-rank in LDS + scatter + BEV (fused, no partials).
// 64 blocks x 256 threads. Each block stages all 4096 keys in LDS (32 KB),
// thread (l = tid&63, q = tid>>6) counts keys < key_i over j-chunk q (1024 j,
// LDS broadcast: all lanes of a wave read the same word). Then tid<64 sums the
// 4 partials and scatters box/BEV/score/label to sorted slot r.
// Also zero-inits nbrw and the NMS flag (after the workspace poison fill).
__global__ void __launch_bounds__(256) k_prep(const float* __restrict__ scores,
                                              const float* __restrict__ boxes9,
                                              const int* __restrict__ labels,
                                              float* __restrict__ box9s, float4* __restrict__ bevs,
                                              float* __restrict__ scoress, int* __restrict__ labelss,
                                              u64* __restrict__ nbrw, u32* __restrict__ flag) {
  #pragma clang fp contract(off)
  __shared__ u64 keys[NB];        // 32 KB
  __shared__ u32 part[64][4];
  int tid = threadIdx.x;
  for (int k = tid; k < NB; k += 256) keys[k] = sort_key(scores[k], k);
  if (blockIdx.x == 0 && tid == 0) *flag = 0u;
  __syncthreads();
  int l = tid & 63, q = tid >> 6;
  u64 ki = keys[blockIdx.x * 64 + l];
  int c = 0;
  #pragma unroll 16
  for (int t = 0; t < 1024; ++t) c += (keys[(q << 10) + t] < ki) ? 1 : 0;  // LDS broadcast
  part[l][q] = (u32)c;
  __syncthreads();
  if (tid < 64) {
    int i = blockIdx.x * 64 + tid;
    int r = (int)(part[tid][0] + part[tid][1] + part[tid][2] + part[tid][3]);
    nbrw[i] = 0;
    float b[9];
    #pragma unroll
    for (int f = 0; f < 9; ++f) b[f] = boxes9[i * 9 + f];
    #pragma unroll
    for (int f = 0; f < 9; ++f) box9s[r * 9 + f] = b[f];
    float ang = b[6] - floorf(b[6] / PI_F + 0.5f) * PI_F;
    bool sw = fabsf(ang) >= PI4_F;
    float dx = sw ? b[4] : b[3];
    float dy = sw ? b[3] : b[4];
    bevs[r] = make_float4(b[0] - dx * 0.5f, b[1] - dy * 0.5f,
                          b[0] + dx * 0.5f, b[1] + dy * 0.5f);
    scoress[r] = scores[i];
    labelss[r] = labels[i];
  }
}

// ---------- K2: pairwise over-matrix, 16 tiles per block (1 tile per wave).
// IOU math verbatim (division, contract off): the (iou > thres) boolean must
// match the f32 reference exactly.
__global__ void __launch_bounds__(1024) k_mask(const float4* __restrict__ bevs,
                                               const int* __restrict__ labelss,
                                               const float* __restrict__ scoress,
                                               u64* __restrict__ mask,
                                               u64* __restrict__ nbrw) {
  #pragma clang fp contract(off)
  __shared__ float4 bj[16][64];   // 16 KB
  __shared__ int lj[16][64];      // 4 KB
  int tid = threadIdx.x;
  int waveId = tid >> 6;
  int lane = tid & 63;
  int T = (blockIdx.x << 4) | waveId;     // tile id in [0,4096)
  int it = T >> 6, jt = T & 63;
  int i = (it << 6) | lane;
  int j = (jt << 6) | lane;
  float4 a = bevs[i];
  int la = labelss[i];
  float area_a = (a.z - a.x) * (a.w - a.y);
  bj[waveId][lane] = bevs[j];
  lj[waveId][lane] = labelss[j];
  u64 vj = __ballot(scoress[j] > COND_THRES);   // valid mask of this j-tile
  __syncthreads();
  u64 w = 0;
  #pragma unroll 8
  for (int kk = 0; kk < 64; ++kk) {
    float4 bb = bj[waveId][kk];
    float xmin = fmaxf(a.x, bb.x), ymin = fmaxf(a.y, bb.y);
    float xmax = fminf(a.z, bb.z), ymax = fminf(a.w, bb.w);
    float inter = fmaxf(xmax - xmin, 0.0f) * fmaxf(ymax - ymin, 0.0f);
    float area_b = (bb.z - bb.x) * (bb.w - bb.y);
    float iou = inter / fmaxf(area_a + area_b - inter, 1e-6f);
    if ((iou > IOU_THRES) && (la == lj[waveId][kk])) w |= (1ull << kk);
  }
  mask[(u64)i * NW + jt] = w;
  if (jt <= it) {
    u64 below = (jt < it) ? ~0ull : ((1ull << lane) - 1ull);
    if (w & vj & below) atomicOr(&nbrw[i], 1ull << jt);
  }
}

// ---------- K3: NMS (block 0) + merge (all blocks), one-way flag handoff.
// Block 0 runs the atomic-free NMS fixpoint (verbatim), publishes keptOut with
// ONE release fence (its single wave's vmcnt covers all 64 stores), then
// atomicExch(flag,1). Blocks 1..255 poll flag with a device-scope RMW (the
// coherent pattern proven in earlier rounds) + ONE acquire fence each.
// Total fence cost: 1 wbl2 + 255 inv (vs 16k in the failed full-barrier fusion).
// Co-residency guaranteed: 256 blocks, <=27 KB LDS, block 0 dispatched first.
__global__ void __launch_bounds__(1024) k_nmsmerge(
    const u64* __restrict__ mask, const u64* __restrict__ nbrw,
    const float* __restrict__ scoress,
    const float* __restrict__ box9s, const int* __restrict__ labelss,
    const float* __restrict__ w1, const float* __restrict__ b1,
    const float* __restrict__ w2, const float* __restrict__ b2,
    const float* __restrict__ w3, const float* __restrict__ b3,
    u64* __restrict__ keptOut, u32* __restrict__ flag,
    float* __restrict__ out) {
  #pragma clang fp contract(off)
  __shared__ __align__(16) char pool[16 * 1600];
  __shared__ u64 nms_decided[64], nms_kept[64];
  __shared__ int nms_wavePending[16];
  __shared__ int nms_any;
  const int tid = threadIdx.x;
  const int bid = blockIdx.x;
  const int waveId = tid >> 6;
  const int lane = tid & 63;

  if (bid == 0) {
    // ===== NMS fixpoint (verbatim from passing round-1 kernel) =====
    u64 dcache[4], kcache[4];
    #pragma unroll
    for (int s = 0; s < 4; ++s) {
      int i = tid + (s << 10);
      bool v = scoress[i] > COND_THRES;
      u64 vw = __ballot(v);
      dcache[s] = ~vw;
      kcache[s] = 0;
      if (lane == 0) {
        int wi = waveId + (s << 4);
        nms_decided[wi] = ~vw;
        nms_kept[wi] = 0;
      }
    }
    u64 cw0[4], cw1[4];
    u32 meta[4];   // [5:0] idx0, [11:6] idx1, [13:12] n(min 2), [14] overflow
    #pragma unroll
    for (int s = 0; s < 4; ++s) {
      int i = tid + (s << 10);
      int wi = i >> 6;
      u64 bit = 1ull << (i & 63);
      u64 t = nbrw[i];
      int n = 0; u32 ovf = 0;
      u64 c0 = 0, c1 = 0; u32 i0 = 0, i1 = 0;
      while (t) {
        int w = __builtin_ctzll(t);
        t &= t - 1;
        u64 below = (w < wi) ? ~0ull : (bit - 1ull);
        u64 m = mask[(u64)i * NW + w] & below;
        if (n == 0)      { c0 = m; i0 = (u32)w; }
        else if (n == 1) { c1 = m; i1 = (u32)w; }
        else ovf = 1;
        ++n;
      }
      cw0[s] = c0; cw1[s] = c1;
      meta[s] = i0 | (i1 << 6) | ((u32)(n > 2 ? 2 : n) << 12) | (ovf << 14);
    }
    __syncthreads();
    while (true) {
      bool pend = false;
      #pragma unroll
      for (int s = 0; s < 4; ++s) {
        bool mine_und = !((dcache[s] >> lane) & 1ull);
        bool dec = false, keepme = false;
        if (mine_und) {
          bool hasU = false, hasK = false;
          u32 mt = meta[s];
          if (!(mt & (1u << 14))) {
            int n = (mt >> 12) & 3;
            if (n >= 1) {
              int w = mt & 63;
              u64 dw = nms_decided[w], kw = nms_kept[w];
              hasU = (cw0[s] & ~dw) != 0ull;
              hasK = (cw0[s] & kw) != 0ull;
            }
            if (n >= 2) {
              int w = (mt >> 6) & 63;
              u64 dw = nms_decided[w], kw = nms_kept[w];
              hasU = hasU || ((cw1[s] & ~dw) != 0ull);
              hasK = hasK || ((cw1[s] & kw) != 0ull);
            }
          } else {
            int i = tid + (s << 10);
            int wi = i >> 6;
            u64 bit = 1ull << (i & 63);
            u64 t = nbrw[i];
            while (t) {
              int w = __builtin_ctzll(t);
              t &= t - 1;
              u64 below = (w < wi) ? ~0ull : (bit - 1ull);
              u64 m = mask[(u64)i * NW + w] & below;
              hasU = hasU || ((m & ~nms_decided[w]) != 0ull);
              hasK = hasK || ((m & nms_kept[w]) != 0ull);
            }
          }
          dec = !hasU;
          keepme = !hasK;
        }
        u64 b_nd = __ballot(dec);
        u64 b_nk = __ballot(dec && keepme);
        dcache[s] |= b_nd;
        kcache[s] |= b_nk;
        pend |= (mine_und && !dec);
      }
      u64 pw = __ballot(pend);
      if (lane == 0) nms_wavePending[waveId] = (pw != 0ull) ? 1 : 0;
      __syncthreads();
      if (lane == 0) {
        #pragma unroll
        for (int s = 0; s < 4; ++s) {
          int wi = waveId + (s << 4);
          nms_decided[wi] = dcache[s];
          nms_kept[wi] = kcache[s];
        }
      }
      if (tid == 0) {
        int any = 0;
        #pragma unroll
        for (int w = 0; w < 16; ++w) any |= nms_wavePending[w];
        nms_any = any;
      }
      __syncthreads();
      if (!nms_any) break;
    }
    // ===== publish: wave 0 stores keptOut; its own vmcnt covers all stores =====
    if (tid < 64) {
      keptOut[tid] = nms_kept[tid];
      __builtin_amdgcn_fence(__ATOMIC_RELEASE, "agent");   // waits wave vmcnt, wb L2
      if (tid == 0) atomicExch(flag, 1u);                  // RMW at coherence point
    }
  } else {
    // ===== consumers: bounded RMW poll + one acquire fence =====
    if (tid == 0) {
      int guard = 0;
      while (atomicAdd(flag, 0u) == 0u && guard < (1 << 21)) {
        __builtin_amdgcn_s_sleep(32);
        ++guard;
      }
      __builtin_amdgcn_fence(__ATOMIC_ACQUIRE, "agent");   // inv stale L2 lines
    }
    __syncthreads();
    if (tid < 64) nms_kept[tid] = keptOut[tid];
  }
  __syncthreads();

  // ===== merge (verbatim round-2 S5, which passed): 1 box per wave =====
  {
    int i = (bid << 4) | waveId;                  // sorted box id
    char* ws5 = pool + waveId * 1600;             // per-wave scratch (disjoint)
    float (*ob)[7]  = (float(*)[7])(ws5);         // 560 B
    float (*h1)[HH] = (float(*)[HH])(ws5 + 560);  // 448 B
    float (*h2)[HH] = (float(*)[HH])(ws5 + 1008); // 448 B
    float* res      = (float*)(ws5 + 1456);       // 28 B
    int* candList   = (int*)(ws5 + 1484);         // 80 B
    bool active = (nms_kept[i >> 6] >> (i & 63)) & 1ull;
    u64 wq = 0;
    int cnt = 0;
    if (active) {
      u64 w = mask[(u64)i * NW + lane];
      int hiw = i >> 6;
      u64 below = (1ull << (i & 63)) - 1ull;
      while (w) {
        int b = __builtin_ctzll(w);
        w &= w - 1;
        int j = (lane << 6) | b;
        if (scoress[j] > COND_THRES) {
          // claimed := exists kept k < i with over(k, j)
          const u64* rowj = mask + (u64)j * NW;
          u64 found = rowj[hiw] & nms_kept[hiw] & below;
          for (int ww = 0; ww < hiw; ++ww) found |= rowj[ww] & nms_kept[ww];
          if (!found) { wq |= (1ull << b); cnt++; }
        }
      }
    }
    int incl = cnt;
    #pragma unroll
    for (int off = 1; off < 64; off <<= 1) {
      int v = __shfl_up(incl, off);
      if (lane >= off) incl += v;
    }
    int excl = incl - cnt;
    int count = __shfl(incl, 63);
    bool merged = active && (count > 1);
    if (merged && wq) {
      int pos = excl;
      u64 ww = wq;
      while (ww && pos < MM) {
        int b = __builtin_ctzll(ww);
        ww &= ww - 1;
        candList[pos++] = (lane << 6) | b;
      }
    }
    __syncthreads();                              // B1
    int nc = count < MM ? count : MM;
    if (merged && lane < MM) {
      if (lane < nc) {
        int j = candList[lane];
        #pragma unroll
        for (int f = 0; f < 7; ++f) ob[lane][f] = box9s[j * 9 + f];
      } else {
        #pragma unroll
        for (int f = 0; f < 7; ++f) ob[lane][f] = 0.0f;
      }
    }
    __syncthreads();                              // B2
    if (merged) {
      for (int o = lane; o < 7 * HH; o += 64) {
        int f = o >> 4, hh = o & 15;
        float acc = b1[hh];
        #pragma unroll
        for (int m = 0; m < MM; ++m) acc += ob[m][f] * w1[m * HH + hh];
        h1[f][hh] = fmaxf(acc, 0.0f);
      }
    }
    __syncthreads();                              // B3
    if (merged) {
      for (int o = lane; o < 7 * HH; o += 64) {
        int f = o >> 4, oo = o & 15;
        float acc = b2[oo];
        #pragma unroll
        for (int k = 0; k < HH; ++k) acc += h1[f][k] * w2[k * HH + oo];
        h2[f][oo] = fmaxf(acc, 0.0f);
      }
    }
    __syncthreads();                              // B4
    if (merged && lane < 7) {
      float acc = b3[0];
      #pragma unroll
      for (int k = 0; k < HH; ++k) acc += h2[lane][k] * w3[k];
      if (lane >= 3 && lane < 6) acc = fmaxf(acc, 1e-5f);
      res[lane] = acc;
    }
    __syncthreads();                              // B5
    if (lane < 9) {
      float v = box9s[i * 9 + lane];
      if (merged && lane < 7) v = res[lane];
      out[i * 9 + lane] = v;
    }
    if (lane == 0) {
      out[NB * 9 + i]          = scoress[i];
      out[NB * 9 + NB + i]     = (float)labelss[i];
      out[NB * 9 + 2 * NB + i] = active ? 1.0f : 0.0f;
    }
  }
}

extern "C" void kernel_launch(void* const* d_in, const int* in_sizes, int n_in,
                              void* d_out, int out_size, void* d_ws, size_t ws_size,
                              hipStream_t stream) {
  const float* boxes9 = (const float*)d_in[0];
  const float* scores = (const float*)d_in[1];
  const int*   labels = (const int*)d_in[2];
  const float* w1 = (const float*)d_in[3];
  const float* b1 = (const float*)d_in[4];
  const float* w2 = (const float*)d_in[5];
  const float* b2 = (const float*)d_in[6];
  const float* w3 = (const float*)d_in[7];
  const float* b3 = (const float*)d_in[8];
  char* ws = (char*)d_ws;
  u64*    kept    = (u64*)(ws + WS_KEPT);
  u32*    flag    = (u32*)(ws + WS_FLAG);
  u64*    mask    = (u64*)(ws + WS_MASK);
  float*  box9s   = (float*)(ws + WS_BOX9S);
  float4* bevs    = (float4*)(ws + WS_BEVS);
  float*  scoress = (float*)(ws + WS_SCORES);
  int*    labelss = (int*)(ws + WS_LABELS);
  u64*    nbrw    = (u64*)(ws + WS_NBRW);
  float*  out     = (float*)d_out;

  hipLaunchKernelGGL(k_prep, dim3(64),  dim3(256),  0, stream,
                     scores, boxes9, labels, box9s, bevs, scoress, labelss, nbrw, flag);
  hipLaunchKernelGGL(k_mask, dim3(256), dim3(1024), 0, stream,
                     bevs, labelss, scoress, mask, nbrw);
  hipLaunchKernelGGL(k_nmsmerge, dim3(256), dim3(1024), 0, stream,
                     mask, nbrw, scoress, box9s, labelss,
                     w1, b1, w2, b2, w3, b3, kept, flag, out);
}